// Round 7
// baseline (204.236 us; speedup 1.0000x reference)
//
#include <hip/hip_runtime.h>
#include <hip/hip_bf16.h>

// ProbsNet: out = mean over 5 of [p_m @ tmp_{0 or 1}]
//   tmp_t[i] = sum_d sigmoid(pB*(pBEV*BEV + ST_t[i,d])) * W_t[i,d]
// R5: 8-deep per-wave MLP didn't move 62us -> not per-wave MLP.
// R6: partial-vmcnt asm pipeline -> correctness race (compiler spills also
//     count in vmcnt). Abandoned.
// R7: phase-lock test, zero asm: ONE persistent generation (2048 blocks =
//     exactly 8/CU, 32 waves/CU), barrier-free grid-stride loop. Waves
//     desynchronize -> continuous memory request flow (m146 pattern).

#define D_DIM      131072
#define N_ROWS     84
#define ROW_F4     (D_DIM / 4)             // 32768 float4 per row (2^15)
#define TENSOR_F4  (N_ROWS * ROW_F4)       // 2752512 f4 per tensor pair
#define TOTAL_F4   (2 * TENSOR_F4)         // 5505024
#define GRID       2048                    // exactly 8 blocks/CU
#define NTHREADS   (GRID * 256)            // 524288 -> 10.5 iters/thread

typedef float f32x4 __attribute__((ext_vector_type(4)));

// entry t of calc_probs(logits): i=t/21; r=t%21
//   r==0 -> p_i ; else r-=1, j=r/5, s=r%5: s==0 -> p_i*p_j else p_i*p_j*p_{s-1}
__device__ inline float prob_entry(const float* __restrict__ logits, int t) {
    float l0 = logits[0], l1 = logits[1], l2 = logits[2], l3 = logits[3];
    float m  = fmaxf(fmaxf(l0, l1), fmaxf(l2, l3));
    float e0 = __expf(l0 - m), e1 = __expf(l1 - m);
    float e2 = __expf(l2 - m), e3 = __expf(l3 - m);
    float inv = 1.0f / (e0 + e1 + e2 + e3);
    float p[4] = {e0 * inv, e1 * inv, e2 * inv, e3 * inv};
    int i = t / 21;
    int r = t - i * 21;
    if (r == 0) return p[i];
    r -= 1;
    int j = r / 5;
    int s = r - j * 5;
    float v = p[i] * p[j];
    return (s == 0) ? v : v * p[s - 1];
}

// w * sigmoid(pb*(bev+s)) = w * rcp(1 + exp2(a*s + ab)), a = -pb*log2(e)
__device__ inline float sigdot(float w, float s, float a, float ab) {
    float e = __builtin_amdgcn_exp2f(fmaf(a, s, ab));
    return w * __builtin_amdgcn_rcpf(1.0f + e);
}

__global__ __launch_bounds__(256, 8) void probsnet_main(
    const float* __restrict__ BEV,
    const float* __restrict__ ST0, const float* __restrict__ W0,
    const float* __restrict__ ST1, const float* __restrict__ W1,
    const float* __restrict__ probs0, const float* __restrict__ probs1,
    const float* __restrict__ probs2, const float* __restrict__ probs3,
    const float* __restrict__ probs4,
    const float* __restrict__ pBEV, const float* __restrict__ pB,
    float* __restrict__ partials)
{
    const int t    = threadIdx.x;
    const int gtid = blockIdx.x * 256 + t;

    const float pb  = pB[0];
    const float bev = pBEV[0] * BEV[0];
    const float a   = -pb * 1.4426950408889634f;   // -pb*log2(e)
    const float ab  = a * bev;

    // Softmax-expansion weights for all rows of both tensor pairs.
    __shared__ float wrow[2 * N_ROWS];
    if (t < N_ROWS) {
        wrow[t] = prob_entry(probs0, t);
    } else if (t < 2 * N_ROWS) {
        const int r = t - N_ROWS;
        wrow[t] = prob_entry(probs1, r) + prob_entry(probs2, r)
                + prob_entry(probs3, r) + prob_entry(probs4, r);
    }
    __syncthreads();   // the ONLY barrier before the final reduce

    const f32x4* __restrict__ st0 = (const f32x4*)ST0;
    const f32x4* __restrict__ w0  = (const f32x4*)W0;
    const f32x4* __restrict__ st1 = (const f32x4*)ST1;
    const f32x4* __restrict__ w1  = (const f32x4*)W1;

    // Barrier-free grid-stride loop: waves drift apart in phase after the
    // first iteration -> memory requests flow continuously instead of the
    // R1-R5 burst/drain oscillation.
    float acc = 0.0f;
    for (int idx = gtid; idx < TOTAL_F4; idx += NTHREADS) {
        const int  tensor = (idx >= TENSOR_F4) ? 1 : 0;
        const int  il     = idx - tensor * TENSOR_F4;
        const f32x4 s4 = tensor ? st1[il] : st0[il];
        const f32x4 w4 = tensor ? w1[il]  : w0[il];
        const float w  = wrow[(il >> 15) + tensor * N_ROWS];
        float c4;
        c4  = sigdot(w4[0], s4[0], a, ab);
        c4 += sigdot(w4[1], s4[1], a, ab);
        c4 += sigdot(w4[2], s4[2], a, ab);
        c4 += sigdot(w4[3], s4[3], a, ab);
        acc = fmaf(w, c4, acc);
    }

    // wave64 shuffle reduction (weights already applied per element-chunk)
    #pragma unroll
    for (int off = 32; off > 0; off >>= 1)
        acc += __shfl_down(acc, off, 64);

    __shared__ float red[4];
    const int wave = t >> 6;
    const int lane = t & 63;
    if (lane == 0) red[wave] = acc;
    __syncthreads();

    if (t == 0)
        partials[blockIdx.x] = red[0] + red[1] + red[2] + red[3];
}

__global__ __launch_bounds__(256) void probsnet_reduce(
    const float* __restrict__ partials, float* __restrict__ out)
{
    const int t = threadIdx.x;
    float acc = 0.0f;
    #pragma unroll
    for (int k = 0; k < GRID / 256; ++k)   // 8 partials per thread
        acc += partials[t + k * 256];

    #pragma unroll
    for (int off = 32; off > 0; off >>= 1)
        acc += __shfl_down(acc, off, 64);

    __shared__ float red[4];
    const int wave = t >> 6;
    const int lane = t & 63;
    if (lane == 0) red[wave] = acc;
    __syncthreads();

    if (t == 0)
        out[0] = (red[0] + red[1] + red[2] + red[3]) * 0.2f;
}

extern "C" void kernel_launch(void* const* d_in, const int* in_sizes, int n_in,
                              void* d_out, int out_size, void* d_ws, size_t ws_size,
                              hipStream_t stream) {
    // setup_inputs order:
    // 0=BEV(1) 1=ST0 2=Weight0 3=ST1 4=Weight1 5=Problem(int,unused)
    // 6..10=probs0..probs4(4) 11=pBEV(1) 12=pB(1)
    const float* BEV    = (const float*)d_in[0];
    const float* ST0    = (const float*)d_in[1];
    const float* W0     = (const float*)d_in[2];
    const float* ST1    = (const float*)d_in[3];
    const float* W1     = (const float*)d_in[4];
    const float* probs0 = (const float*)d_in[6];
    const float* probs1 = (const float*)d_in[7];
    const float* probs2 = (const float*)d_in[8];
    const float* probs3 = (const float*)d_in[9];
    const float* probs4 = (const float*)d_in[10];
    const float* pBEV   = (const float*)d_in[11];
    const float* pB     = (const float*)d_in[12];

    float* partials = (float*)d_ws;          // 2048 floats = 8 KB scratch
    float* out      = (float*)d_out;

    probsnet_main<<<GRID, 256, 0, stream>>>(
        BEV, ST0, W0, ST1, W1,
        probs0, probs1, probs2, probs3, probs4,
        pBEV, pB, partials);

    probsnet_reduce<<<1, 256, 0, stream>>>(partials, out);
}